// Round 2
// baseline (5923.803 us; speedup 1.0000x reference)
//
#include <hip/hip_runtime.h>
#include <cstdint>
#include <cstddef>

#define IN_C 128
#define HID_C 128
#define OUT_C 64

__device__ __forceinline__ float b2f(unsigned short s) {
    return __uint_as_float(((unsigned)s) << 16);
}
__device__ __forceinline__ unsigned short f2b(float f) {
    unsigned u = __float_as_uint(f);
    unsigned r = (u + 0x7fffu + ((u >> 16) & 1u)) >> 16;  // round-to-nearest-even
    return (unsigned short)r;
}

// Segment-sum of 128-ch f32 features: 32 threads/edge, float4 (4 ch) per thread.
// Also accumulates degree (lane q==0).
__global__ __launch_bounds__(256) void scatter_f32_kernel(
    const float* __restrict__ feat, const int* __restrict__ src,
    const int* __restrict__ dst, float* __restrict__ agg,
    float* __restrict__ deg, int E) {
    long long tid = (long long)blockIdx.x * blockDim.x + threadIdx.x;
    int e = (int)(tid >> 5);
    int q = (int)(tid & 31);
    if (e >= E) return;
    int s = src[e];
    int d = dst[e];
    float4 v = ((const float4*)feat)[(size_t)s * 32 + q];
    float* a = agg + (size_t)d * 128 + (size_t)q * 4;
    unsafeAtomicAdd(a + 0, v.x);
    unsafeAtomicAdd(a + 1, v.y);
    unsafeAtomicAdd(a + 2, v.z);
    unsafeAtomicAdd(a + 3, v.w);
    if (q == 0) unsafeAtomicAdd(deg + d, 1.0f);
}

// Segment-sum of 128-ch bf16 features (h lives in d_out as bf16).
__global__ __launch_bounds__(256) void scatter_bf16_kernel(
    const unsigned short* __restrict__ feat, const int* __restrict__ src,
    const int* __restrict__ dst, float* __restrict__ agg, int E) {
    long long tid = (long long)blockIdx.x * blockDim.x + threadIdx.x;
    int e = (int)(tid >> 5);
    int q = (int)(tid & 31);
    if (e >= E) return;
    int s = src[e];
    int d = dst[e];
    ushort4 v = ((const ushort4*)feat)[(size_t)s * 32 + q];
    float* a = agg + (size_t)d * 128 + (size_t)q * 4;
    unsafeAtomicAdd(a + 0, b2f(v.x));
    unsafeAtomicAdd(a + 1, b2f(v.y));
    unsafeAtomicAdd(a + 2, b2f(v.z));
    unsafeAtomicAdd(a + 3, b2f(v.w));
}

// h(bf16) = relu( (agg/deg) @ Wl + bl + x @ Wr ), 128->128.
// Weights staged bf16 in LDS (64 KB both). Thread: 4 channels (c4 of 32) x 1 row (rh of 8).
__global__ __launch_bounds__(256) void gemm1_kernel(
    const float* __restrict__ x, const float* __restrict__ agg,
    const float* __restrict__ deg, const float* __restrict__ Wl,
    const float* __restrict__ bl, const float* __restrict__ Wr,
    unsigned short* __restrict__ hb, int N) {
    __shared__ unsigned short sWl[IN_C * HID_C];
    __shared__ unsigned short sWr[IN_C * HID_C];
    int tid = threadIdx.x;
    for (int i = tid; i < IN_C * HID_C; i += 256) {
        sWl[i] = f2b(Wl[i]);
        sWr[i] = f2b(Wr[i]);
    }
    __syncthreads();
    int c4 = tid & 31;   // channels c4*4 .. c4*4+3
    int rh = tid >> 5;   // 0..7 -> 8 rows per block-iteration
    float4 bias = ((const float4*)bl)[c4];
    const ushort4* sWl4 = (const ushort4*)sWl;  // [k*32 + c4]
    const ushort4* sWr4 = (const ushort4*)sWr;
    for (int row0 = blockIdx.x * 8; row0 < N; row0 += gridDim.x * 8) {
        int r = row0 + rh;
        if (r >= N) continue;
        float invd = 1.0f / fmaxf(deg[r], 1.0f);
        const float4* av = (const float4*)(agg + (size_t)r * 128);
        const float4* xv = (const float4*)(x + (size_t)r * 128);
        float4 acc = bias;
        for (int kc = 0; kc < 32; ++kc) {
            float4 m4 = av[kc];
            float4 x4 = xv[kc];
            float ms[4] = {m4.x * invd, m4.y * invd, m4.z * invd, m4.w * invd};
            float xs[4] = {x4.x, x4.y, x4.z, x4.w};
#pragma unroll
            for (int j = 0; j < 4; ++j) {
                int k = kc * 4 + j;
                ushort4 wl = sWl4[k * 32 + c4];
                ushort4 wr = sWr4[k * 32 + c4];
                float mk = ms[j], xk = xs[j];
                acc.x += mk * b2f(wl.x) + xk * b2f(wr.x);
                acc.y += mk * b2f(wl.y) + xk * b2f(wr.y);
                acc.z += mk * b2f(wl.z) + xk * b2f(wr.z);
                acc.w += mk * b2f(wl.w) + xk * b2f(wr.w);
            }
        }
        ushort4 o;
        o.x = f2b(fmaxf(acc.x, 0.0f));
        o.y = f2b(fmaxf(acc.y, 0.0f));
        o.z = f2b(fmaxf(acc.z, 0.0f));
        o.w = f2b(fmaxf(acc.w, 0.0f));
        ((ushort4*)(hb + (size_t)r * 128))[c4] = o;
    }
}

// out(f32) = log_softmax( (agg/deg) @ Wl2 + bl2 + h @ Wr2 ), 128->64.
// h is bf16 and ALIASES out (same byte range per row: 128*2B == 64*4B).
// Safe: row r is touched only by 16 lanes of one wave; the out-store is
// dataflow-dependent on every h-load of that row.
__global__ __launch_bounds__(256) void gemm2_kernel(
    const unsigned short* __restrict__ hb, const float* __restrict__ agg,
    const float* __restrict__ deg, const float* __restrict__ Wl,
    const float* __restrict__ bl, const float* __restrict__ Wr,
    float* __restrict__ out, int N) {
    __shared__ unsigned short sWl[HID_C * OUT_C];
    __shared__ unsigned short sWr[HID_C * OUT_C];
    int tid = threadIdx.x;
    for (int i = tid; i < HID_C * OUT_C; i += 256) {
        sWl[i] = f2b(Wl[i]);
        sWr[i] = f2b(Wr[i]);
    }
    __syncthreads();
    int c4 = tid & 15;   // channels c4*4 .. c4*4+3  (64 total)
    int rh = tid >> 4;   // 0..15 -> 16 rows per block-iteration
    float4 bias = ((const float4*)bl)[c4];
    const ushort4* sWl4 = (const ushort4*)sWl;  // [k*16 + c4]
    const ushort4* sWr4 = (const ushort4*)sWr;
    for (int row0 = blockIdx.x * 16; row0 < N; row0 += gridDim.x * 16) {
        int r = row0 + rh;
        if (r >= N) continue;  // N % 16 == 0 -> no intra-wave divergence
        float invd = 1.0f / fmaxf(deg[r], 1.0f);
        const float4* av = (const float4*)(agg + (size_t)r * 128);
        const ushort4* hv = (const ushort4*)(hb + (size_t)r * 128);
        float4 acc = bias;
        for (int kc = 0; kc < 32; ++kc) {
            float4 m4 = av[kc];
            ushort4 h4 = hv[kc];
            float ms[4] = {m4.x * invd, m4.y * invd, m4.z * invd, m4.w * invd};
            float hs[4] = {b2f(h4.x), b2f(h4.y), b2f(h4.z), b2f(h4.w)};
#pragma unroll
            for (int j = 0; j < 4; ++j) {
                int k = kc * 4 + j;
                ushort4 wl = sWl4[k * 16 + c4];
                ushort4 wr = sWr4[k * 16 + c4];
                float mk = ms[j], hk = hs[j];
                acc.x += mk * b2f(wl.x) + hk * b2f(wr.x);
                acc.y += mk * b2f(wl.y) + hk * b2f(wr.y);
                acc.z += mk * b2f(wl.z) + hk * b2f(wr.z);
                acc.w += mk * b2f(wl.w) + hk * b2f(wr.w);
            }
        }
        // log_softmax over the row's 64 channels: 16 lanes x 4 each (xor-closed group)
        float m = fmaxf(fmaxf(acc.x, acc.y), fmaxf(acc.z, acc.w));
        for (int off = 8; off; off >>= 1) m = fmaxf(m, __shfl_xor(m, off));
        float s = expf(acc.x - m) + expf(acc.y - m) + expf(acc.z - m) + expf(acc.w - m);
        for (int off = 8; off; off >>= 1) s += __shfl_xor(s, off);
        float lse = m + logf(s);
        float4 o = {acc.x - lse, acc.y - lse, acc.z - lse, acc.w - lse};
        ((float4*)(out + (size_t)r * 64))[c4] = o;
    }
}

extern "C" void kernel_launch(void* const* d_in, const int* in_sizes, int n_in,
                              void* d_out, int out_size, void* d_ws, size_t ws_size,
                              hipStream_t stream) {
    const float* x   = (const float*)d_in[0];
    const int*   ei  = (const int*)d_in[1];
    const float* Wl1 = (const float*)d_in[2];
    const float* bl1 = (const float*)d_in[3];
    const float* Wr1 = (const float*)d_in[4];
    const float* Wl2 = (const float*)d_in[5];
    const float* bl2 = (const float*)d_in[6];
    const float* Wr2 = (const float*)d_in[7];
    float* out = (float*)d_out;

    int N = in_sizes[0] / IN_C;
    int E = in_sizes[1] / 2;
    const int* src = ei;
    const int* dst = ei + E;

    // Workspace (51.6 MB): agg f32[N*128] | deg f32[N].
    // h (bf16, N*128 = 25.6 MB) lives inside d_out (out_size*4 B = 25.6 MB).
    float* agg = (float*)d_ws;
    float* deg = agg + (size_t)N * 128;
    unsigned short* hb = (unsigned short*)d_out;

    hipMemsetAsync(agg, 0, (size_t)N * 128 * sizeof(float), stream);
    hipMemsetAsync(deg, 0, (size_t)N * sizeof(float), stream);

    long long nthr = (long long)E * 32;
    int sblocks = (int)((nthr + 255) / 256);

    // Layer 1: aggregate x, then h = relu(mean@Wl1 + bl1 + x@Wr1)  (bf16 in d_out)
    scatter_f32_kernel<<<sblocks, 256, 0, stream>>>(x, src, dst, agg, deg, E);
    gemm1_kernel<<<512, 256, 0, stream>>>(x, agg, deg, Wl1, bl1, Wr1, hb, N);

    // Layer 2: re-zero agg, aggregate h, then out = log_softmax(mean@Wl2 + bl2 + h@Wr2)
    hipMemsetAsync(agg, 0, (size_t)N * 128 * sizeof(float), stream);
    scatter_bf16_kernel<<<sblocks, 256, 0, stream>>>(hb, src, dst, agg, E);
    gemm2_kernel<<<1024, 256, 0, stream>>>(hb, agg, deg, Wl2, bl2, Wr2, out, N);
}

// Round 3
// 1233.269 us; speedup vs baseline: 4.8033x; 4.8033x over previous
//
#include <hip/hip_runtime.h>
#include <cstdint>
#include <cstddef>

#define IN_C 128
#define HID_C 128
#define OUT_C 64

__device__ __forceinline__ float b2f(unsigned short s) {
    return __uint_as_float(((unsigned)s) << 16);
}
__device__ __forceinline__ unsigned short f2b(float f) {
    unsigned u = __float_as_uint(f);
    unsigned r = (u + 0x7fffu + ((u >> 16) & 1u)) >> 16;  // round-to-nearest-even
    return (unsigned short)r;
}

// ---- CSR build: histogram of dst ----
__global__ __launch_bounds__(256) void hist_kernel(
    const int* __restrict__ dst, int* __restrict__ counts, int E) {
    int e = blockIdx.x * 256 + threadIdx.x;
    if (e < E) atomicAdd(&counts[dst[e]], 1);
}

// ---- CSR build: single-block exclusive scan of counts -> offs ----
__global__ __launch_bounds__(1024) void scan_kernel(
    const int* __restrict__ counts, int* __restrict__ offs, int N) {
    __shared__ int ps[1024];
    int t = threadIdx.x;
    int CH = (N + 1023) >> 10;
    int beg = t * CH, end = min(beg + CH, N);
    int s = 0;
    for (int i = beg; i < end; ++i) s += counts[i];
    ps[t] = s;
    __syncthreads();
    for (int off = 1; off < 1024; off <<= 1) {
        int v = 0;
        if (t >= off) v = ps[t - off];
        __syncthreads();
        if (t >= off) ps[t] += v;
        __syncthreads();
    }
    int run = ps[t] - s;  // exclusive prefix at beg
    for (int i = beg; i < end; ++i) { offs[i] = run; run += counts[i]; }
}

// ---- CSR build: scatter src ids into buckets. Destroys offs -> bucket ends. ----
__global__ __launch_bounds__(256) void bucket_kernel(
    const int* __restrict__ src, const int* __restrict__ dst,
    int* __restrict__ offs, int* __restrict__ csr, int E) {
    int e = blockIdx.x * 256 + threadIdx.x;
    if (e < E) {
        int pos = atomicAdd(&offs[dst[e]], 1);
        csr[pos] = src[e];
    }
}

// ---- Layer 1: h(bf16) = relu(mean_{neigh} x @ Wl + bl + x @ Wr), 128->128 ----
// Block = 256 thr = 8 groups of 32 lanes; group g handles row r = blk*8+g.
// Gather phase: lane q accumulates channels q*4..q*4+3 of the neighbor mean.
// Mean + self row parked in LDS, then each lane computes 4 output channels.
__global__ __launch_bounds__(256) void gemm1_kernel(
    const float* __restrict__ x, const int* __restrict__ counts,
    const int* __restrict__ offs, const int* __restrict__ csr,
    const float* __restrict__ Wl, const float* __restrict__ bl,
    const float* __restrict__ Wr, unsigned short* __restrict__ hb, int N) {
    __shared__ unsigned short sWl[IN_C * HID_C];  // 32 KB
    __shared__ unsigned short sWr[IN_C * HID_C];  // 32 KB
    __shared__ float sMean[8][IN_C];              // 4 KB
    __shared__ float sX[8][IN_C];                 // 4 KB
    int tid = threadIdx.x;
    for (int i = tid; i < IN_C * HID_C; i += 256) {
        sWl[i] = f2b(Wl[i]);
        sWr[i] = f2b(Wr[i]);
    }
    int g = tid >> 5, q = tid & 31;
    int r = blockIdx.x * 8 + g;
    if (r < N) {
        int cnt = counts[r];
        int end = offs[r];      // offs was advanced to bucket end
        int beg = end - cnt;
        float4 macc = {0.f, 0.f, 0.f, 0.f};
        for (int i = beg; i < end; ++i) {
            int s = csr[i];  // broadcast across the 32-lane group
            float4 v = ((const float4*)x)[(size_t)s * 32 + q];
            macc.x += v.x; macc.y += v.y; macc.z += v.z; macc.w += v.w;
        }
        float invd = 1.0f / (float)max(cnt, 1);
        macc.x *= invd; macc.y *= invd; macc.z *= invd; macc.w *= invd;
        float4 xr = ((const float4*)x)[(size_t)r * 32 + q];
        *(float4*)&sMean[g][q * 4] = macc;
        *(float4*)&sX[g][q * 4] = xr;
    }
    __syncthreads();
    if (r >= N) return;
    float4 acc = ((const float4*)bl)[q];
    const ushort4* sWl4 = (const ushort4*)sWl;  // [k*32 + c4]
    const ushort4* sWr4 = (const ushort4*)sWr;
    for (int kc = 0; kc < 32; ++kc) {
        float4 m4 = *(const float4*)&sMean[g][kc * 4];
        float4 x4 = *(const float4*)&sX[g][kc * 4];
        float ms[4] = {m4.x, m4.y, m4.z, m4.w};
        float xs[4] = {x4.x, x4.y, x4.z, x4.w};
#pragma unroll
        for (int j = 0; j < 4; ++j) {
            int k = kc * 4 + j;
            ushort4 wl = sWl4[k * 32 + q];
            ushort4 wr = sWr4[k * 32 + q];
            float mk = ms[j], xk = xs[j];
            acc.x += mk * b2f(wl.x) + xk * b2f(wr.x);
            acc.y += mk * b2f(wl.y) + xk * b2f(wr.y);
            acc.z += mk * b2f(wl.z) + xk * b2f(wr.z);
            acc.w += mk * b2f(wl.w) + xk * b2f(wr.w);
        }
    }
    ushort4 o;
    o.x = f2b(fmaxf(acc.x, 0.0f));
    o.y = f2b(fmaxf(acc.y, 0.0f));
    o.z = f2b(fmaxf(acc.z, 0.0f));
    o.w = f2b(fmaxf(acc.w, 0.0f));
    ((ushort4*)(hb + (size_t)r * 128))[q] = o;
}

// ---- Layer 2: out(f32) = log_softmax(mean_{neigh} h @ Wl2 + bl2 + h @ Wr2), 128->64 ----
// Block = 256 thr = 16 groups of 16 lanes; group g handles row r = blk*16+g.
// Gather: lane q accumulates channels {q*4.., (q+16)*4..} (two float4s) of mean h.
__global__ __launch_bounds__(256) void gemm2_kernel(
    const unsigned short* __restrict__ hb, const int* __restrict__ counts,
    const int* __restrict__ offs, const int* __restrict__ csr,
    const float* __restrict__ Wl, const float* __restrict__ bl,
    const float* __restrict__ Wr, float* __restrict__ out, int N) {
    __shared__ unsigned short sWl[HID_C * OUT_C];  // 16 KB
    __shared__ unsigned short sWr[HID_C * OUT_C];  // 16 KB
    __shared__ float sMean[16][HID_C];             // 8 KB
    __shared__ float sH[16][HID_C];                // 8 KB
    int tid = threadIdx.x;
    for (int i = tid; i < HID_C * OUT_C; i += 256) {
        sWl[i] = f2b(Wl[i]);
        sWr[i] = f2b(Wr[i]);
    }
    int g = tid >> 4, q = tid & 15;
    int r = blockIdx.x * 16 + g;
    if (r < N) {
        int cnt = counts[r];
        int end = offs[r];
        int beg = end - cnt;
        float4 m0 = {0.f, 0.f, 0.f, 0.f}, m1 = {0.f, 0.f, 0.f, 0.f};
        for (int i = beg; i < end; ++i) {
            int s = csr[i];
            ushort4 a = ((const ushort4*)hb)[(size_t)s * 32 + q];
            ushort4 b = ((const ushort4*)hb)[(size_t)s * 32 + q + 16];
            m0.x += b2f(a.x); m0.y += b2f(a.y); m0.z += b2f(a.z); m0.w += b2f(a.w);
            m1.x += b2f(b.x); m1.y += b2f(b.y); m1.z += b2f(b.z); m1.w += b2f(b.w);
        }
        float invd = 1.0f / (float)max(cnt, 1);
        m0.x *= invd; m0.y *= invd; m0.z *= invd; m0.w *= invd;
        m1.x *= invd; m1.y *= invd; m1.z *= invd; m1.w *= invd;
        *(float4*)&sMean[g][q * 4] = m0;
        *(float4*)&sMean[g][(q + 16) * 4] = m1;
        ushort4 a = ((const ushort4*)hb)[(size_t)r * 32 + q];
        ushort4 b = ((const ushort4*)hb)[(size_t)r * 32 + q + 16];
        float4 h0 = {b2f(a.x), b2f(a.y), b2f(a.z), b2f(a.w)};
        float4 h1 = {b2f(b.x), b2f(b.y), b2f(b.z), b2f(b.w)};
        *(float4*)&sH[g][q * 4] = h0;
        *(float4*)&sH[g][(q + 16) * 4] = h1;
    }
    __syncthreads();
    if (r >= N) return;
    float4 acc = ((const float4*)bl)[q];
    const ushort4* sWl4 = (const ushort4*)sWl;  // [k*16 + c4]
    const ushort4* sWr4 = (const ushort4*)sWr;
    for (int kc = 0; kc < 32; ++kc) {
        float4 m4 = *(const float4*)&sMean[g][kc * 4];
        float4 h4 = *(const float4*)&sH[g][kc * 4];
        float ms[4] = {m4.x, m4.y, m4.z, m4.w};
        float hs[4] = {h4.x, h4.y, h4.z, h4.w};
#pragma unroll
        for (int j = 0; j < 4; ++j) {
            int k = kc * 4 + j;
            ushort4 wl = sWl4[k * 16 + q];
            ushort4 wr = sWr4[k * 16 + q];
            float mk = ms[j], hk = hs[j];
            acc.x += mk * b2f(wl.x) + hk * b2f(wr.x);
            acc.y += mk * b2f(wl.y) + hk * b2f(wr.y);
            acc.z += mk * b2f(wl.z) + hk * b2f(wr.z);
            acc.w += mk * b2f(wl.w) + hk * b2f(wr.w);
        }
    }
    // log_softmax over the row's 64 channels: 16 lanes x 4 each (xor-closed group)
    float m = fmaxf(fmaxf(acc.x, acc.y), fmaxf(acc.z, acc.w));
    for (int off = 8; off; off >>= 1) m = fmaxf(m, __shfl_xor(m, off));
    float s = expf(acc.x - m) + expf(acc.y - m) + expf(acc.z - m) + expf(acc.w - m);
    for (int off = 8; off; off >>= 1) s += __shfl_xor(s, off);
    float lse = m + logf(s);
    float4 o = {acc.x - lse, acc.y - lse, acc.z - lse, acc.w - lse};
    ((float4*)(out + (size_t)r * 64))[q] = o;
}

extern "C" void kernel_launch(void* const* d_in, const int* in_sizes, int n_in,
                              void* d_out, int out_size, void* d_ws, size_t ws_size,
                              hipStream_t stream) {
    const float* x   = (const float*)d_in[0];
    const int*   ei  = (const int*)d_in[1];
    const float* Wl1 = (const float*)d_in[2];
    const float* bl1 = (const float*)d_in[3];
    const float* Wr1 = (const float*)d_in[4];
    const float* Wl2 = (const float*)d_in[5];
    const float* bl2 = (const float*)d_in[6];
    const float* Wr2 = (const float*)d_in[7];
    float* out = (float*)d_out;

    int N = in_sizes[0] / IN_C;
    int E = in_sizes[1] / 2;
    const int* src = ei;
    const int* dst = ei + E;

    // Workspace (32.8 MB): counts i32[N] | offs i32[N] | csr i32[E] | hb bf16[N*128]
    int* counts = (int*)d_ws;
    int* offs   = counts + N;
    int* csr    = offs + N;
    unsigned short* hb = (unsigned short*)(csr + E);  // byte offset 4*(2N+E) = 7.2e6, 16-aligned

    hipMemsetAsync(counts, 0, (size_t)N * sizeof(int), stream);

    int eblocks = (E + 255) / 256;
    hist_kernel<<<eblocks, 256, 0, stream>>>(dst, counts, E);
    scan_kernel<<<1, 1024, 0, stream>>>(counts, offs, N);
    bucket_kernel<<<eblocks, 256, 0, stream>>>(src, dst, offs, csr, E);

    gemm1_kernel<<<(N + 7) / 8, 256, 0, stream>>>(
        x, counts, offs, csr, Wl1, bl1, Wr1, hb, N);
    gemm2_kernel<<<(N + 15) / 16, 256, 0, stream>>>(
        hb, counts, offs, csr, Wl2, bl2, Wr2, out, N);
}

// Round 4
// 655.926 us; speedup vs baseline: 9.0312x; 1.8802x over previous
//
#include <hip/hip_runtime.h>
#include <cstdint>
#include <cstddef>

#define IN_C 128
#define HID_C 128
#define OUT_C 64

typedef __attribute__((ext_vector_type(8))) short bf16x8;
typedef __attribute__((ext_vector_type(8))) unsigned short u16x8;
typedef __attribute__((ext_vector_type(4))) float f32x4;

__device__ __forceinline__ float b2f(unsigned short s) {
    return __uint_as_float(((unsigned)s) << 16);
}
__device__ __forceinline__ unsigned short f2b(float f) {
    unsigned u = __float_as_uint(f);
    unsigned r = (u + 0x7fffu + ((u >> 16) & 1u)) >> 16;  // round-to-nearest-even
    return (unsigned short)r;
}

// ---- CSR build: histogram of dst ----
__global__ __launch_bounds__(256) void hist_kernel(
    const int* __restrict__ dst, int* __restrict__ counts, int E) {
    int e = blockIdx.x * 256 + threadIdx.x;
    if (e < E) atomicAdd(&counts[dst[e]], 1);
}

// ---- CSR build: single-block exclusive scan of counts -> offs ----
__global__ __launch_bounds__(1024) void scan_kernel(
    const int* __restrict__ counts, int* __restrict__ offs, int N) {
    __shared__ int ps[1024];
    int t = threadIdx.x;
    int CH = (N + 1023) >> 10;
    int beg = t * CH, end = min(beg + CH, N);
    int s = 0;
    for (int i = beg; i < end; ++i) s += counts[i];
    ps[t] = s;
    __syncthreads();
    for (int off = 1; off < 1024; off <<= 1) {
        int v = 0;
        if (t >= off) v = ps[t - off];
        __syncthreads();
        if (t >= off) ps[t] += v;
        __syncthreads();
    }
    int run = ps[t] - s;  // exclusive prefix at beg
    for (int i = beg; i < end; ++i) { offs[i] = run; run += counts[i]; }
}

// ---- CSR build: scatter src ids into buckets. Advances offs -> bucket ends. ----
__global__ __launch_bounds__(256) void bucket_kernel(
    const int* __restrict__ src, const int* __restrict__ dst,
    int* __restrict__ offs, int* __restrict__ csr, int E) {
    int e = blockIdx.x * 256 + threadIdx.x;
    if (e < E) {
        int pos = atomicAdd(&offs[dst[e]], 1);
        csr[pos] = src[e];
    }
}

// ---- Convert x (f32) -> xb (bf16). N*128 = 12.8M elems = 6250 blocks * 256 thr * 8 ----
__global__ __launch_bounds__(256) void convert_kernel(
    const float* __restrict__ x, unsigned short* __restrict__ xb) {
    size_t i = ((size_t)blockIdx.x * 256 + threadIdx.x) * 8;
    float4 u = *(const float4*)(x + i);
    float4 v = *(const float4*)(x + i + 4);
    u16x8 o;
    o[0] = f2b(u.x); o[1] = f2b(u.y); o[2] = f2b(u.z); o[3] = f2b(u.w);
    o[4] = f2b(v.x); o[5] = f2b(v.y); o[6] = f2b(v.z); o[7] = f2b(v.w);
    *(u16x8*)(xb + i) = o;
}

// ---- Gather-mean: mean over CSR neighbors of bf16 features -> bf16 out ----
// 16 lanes per row, ushort8 (16B) per lane. No LDS, low VGPR -> high occupancy.
__global__ __launch_bounds__(256) void agg_mean_kernel(
    const unsigned short* __restrict__ feat, const int* __restrict__ counts,
    const int* __restrict__ ends, const int* __restrict__ csr,
    unsigned short* __restrict__ mean_out, int N) {
    int g = (blockIdx.x * 256 + threadIdx.x) >> 4;  // row id
    int q = threadIdx.x & 15;
    if (g >= N) return;
    int cnt = counts[g];
    int end = ends[g];
    int beg = end - cnt;
    float a0=0.f,a1=0.f,a2=0.f,a3=0.f,a4=0.f,a5=0.f,a6=0.f,a7=0.f;
    int i = beg;
    for (; i + 1 < end; i += 2) {
        int s0 = csr[i], s1 = csr[i + 1];
        u16x8 v0 = *(const u16x8*)(feat + (size_t)s0 * 128 + q * 8);
        u16x8 v1 = *(const u16x8*)(feat + (size_t)s1 * 128 + q * 8);
        a0 += b2f(v0[0]) + b2f(v1[0]); a1 += b2f(v0[1]) + b2f(v1[1]);
        a2 += b2f(v0[2]) + b2f(v1[2]); a3 += b2f(v0[3]) + b2f(v1[3]);
        a4 += b2f(v0[4]) + b2f(v1[4]); a5 += b2f(v0[5]) + b2f(v1[5]);
        a6 += b2f(v0[6]) + b2f(v1[6]); a7 += b2f(v0[7]) + b2f(v1[7]);
    }
    if (i < end) {
        int s0 = csr[i];
        u16x8 v0 = *(const u16x8*)(feat + (size_t)s0 * 128 + q * 8);
        a0 += b2f(v0[0]); a1 += b2f(v0[1]); a2 += b2f(v0[2]); a3 += b2f(v0[3]);
        a4 += b2f(v0[4]); a5 += b2f(v0[5]); a6 += b2f(v0[6]); a7 += b2f(v0[7]);
    }
    float invd = 1.0f / (float)max(cnt, 1);
    u16x8 o;
    o[0] = f2b(a0 * invd); o[1] = f2b(a1 * invd); o[2] = f2b(a2 * invd); o[3] = f2b(a3 * invd);
    o[4] = f2b(a4 * invd); o[5] = f2b(a5 * invd); o[6] = f2b(a6 * invd); o[7] = f2b(a7 * invd);
    *(u16x8*)(mean_out + (size_t)g * 128 + q * 8) = o;
}

// ---- Layer 1 MFMA GEMM: h(bf16) = relu([mean|x](N,256) @ [Wl;Wr](256,128) + bl) ----
// Block = 4 waves; wave handles 16 rows x 128 cols (8 col-tiles of 16x16, K = 8 steps of 32).
// A: steps 0-3 from mb (bf16), steps 4-7 from x (f32, converted in-register).
// B: bf16 in LDS as Bt[n][k], padded k-stride 260 (2-way bank aliasing only).
__global__ __launch_bounds__(256, 2) void gemm1_mfma_kernel(
    const unsigned short* __restrict__ mb, const float* __restrict__ x,
    const float* __restrict__ Wl, const float* __restrict__ bl,
    const float* __restrict__ Wr, unsigned short* __restrict__ hb,
    int N, int ntiles) {
    __shared__ unsigned short sB[128][260];  // 66,560 B
    int tid = threadIdx.x;
    for (int i = tid; i < 128 * 128; i += 256) {
        int k = i >> 7, n = i & 127;
        sB[n][k] = f2b(Wl[i]);        // Wl[k][n]
        sB[n][128 + k] = f2b(Wr[i]);  // Wr[k][n]
    }
    __syncthreads();
    int wave = tid >> 6, lane = tid & 63;
    int quad = lane >> 4, m = lane & 15;
    for (int tile = blockIdx.x; tile < ntiles; tile += gridDim.x) {
        int r0 = tile * 64 + wave * 16;
        int row = min(r0 + m, N - 1);  // A-load row for this lane (clamped)
        f32x4 acc[8];
#pragma unroll
        for (int c = 0; c < 8; ++c) acc[c] = {0.f, 0.f, 0.f, 0.f};
        // K-steps 0..3: A = mean (bf16)
        const bf16x8* mrow = (const bf16x8*)(mb + (size_t)row * 128);
#pragma unroll
        for (int step = 0; step < 4; ++step) {
            bf16x8 af = mrow[step * 4 + quad];
#pragma unroll
            for (int c = 0; c < 8; ++c) {
                bf16x8 bf = *(const bf16x8*)&sB[c * 16 + m][step * 32 + quad * 8];
                acc[c] = __builtin_amdgcn_mfma_f32_16x16x32_bf16(af, bf, acc[c], 0, 0, 0);
            }
        }
        // K-steps 4..7: A = x (f32 -> bf16 in-register)
        const float* xrow = x + (size_t)row * 128;
#pragma unroll
        for (int step = 0; step < 4; ++step) {
            int k0 = step * 32 + quad * 8;
            float4 u = *(const float4*)(xrow + k0);
            float4 v = *(const float4*)(xrow + k0 + 4);
            bf16x8 af;
            af[0] = (short)f2b(u.x); af[1] = (short)f2b(u.y);
            af[2] = (short)f2b(u.z); af[3] = (short)f2b(u.w);
            af[4] = (short)f2b(v.x); af[5] = (short)f2b(v.y);
            af[6] = (short)f2b(v.z); af[7] = (short)f2b(v.w);
#pragma unroll
            for (int c = 0; c < 8; ++c) {
                bf16x8 bf = *(const bf16x8*)&sB[c * 16 + m][128 + step * 32 + quad * 8];
                acc[c] = __builtin_amdgcn_mfma_f32_16x16x32_bf16(af, bf, acc[c], 0, 0, 0);
            }
        }
        // Epilogue: +bias, relu, bf16 store. C/D: col = c*16 + (lane&15), row = r0 + quad*4 + reg
#pragma unroll
        for (int c = 0; c < 8; ++c) {
            int n = c * 16 + m;
            float b = bl[n];
#pragma unroll
            for (int reg = 0; reg < 4; ++reg) {
                int r = r0 + quad * 4 + reg;
                if (r < N) hb[(size_t)r * 128 + n] = f2b(fmaxf(acc[c][reg] + b, 0.f));
            }
        }
    }
}

// ---- Layer 2 MFMA GEMM + log_softmax: out(f32) = lsm([mean2|h](N,256) @ [Wl2;Wr2](256,64) + bl2) ----
// Wave: 16 rows x 64 cols (4 col-tiles). h (bf16) ALIASES out rows byte-for-byte
// (128*2B == 64*4B); all in-wave h reads precede the out store.
__global__ __launch_bounds__(256, 2) void gemm2_mfma_kernel(
    const unsigned short* __restrict__ mb, const unsigned short* __restrict__ hb,
    const float* __restrict__ Wl, const float* __restrict__ bl,
    const float* __restrict__ Wr, float* __restrict__ out,
    int N, int ntiles) {
    __shared__ unsigned short sB[64][260];  // 33,280 B
    int tid = threadIdx.x;
    for (int i = tid; i < 128 * 64; i += 256) {
        int k = i >> 6, n = i & 63;
        sB[n][k] = f2b(Wl[i]);        // Wl2[k][n]
        sB[n][128 + k] = f2b(Wr[i]);  // Wr2[k][n]
    }
    __syncthreads();
    int wave = tid >> 6, lane = tid & 63;
    int quad = lane >> 4, m = lane & 15;
    for (int tile = blockIdx.x; tile < ntiles; tile += gridDim.x) {
        int r0 = tile * 64 + wave * 16;
        int row = min(r0 + m, N - 1);
        f32x4 acc[4];
#pragma unroll
        for (int c = 0; c < 4; ++c) acc[c] = {0.f, 0.f, 0.f, 0.f};
        const bf16x8* mrow = (const bf16x8*)(mb + (size_t)row * 128);
        const bf16x8* hrow = (const bf16x8*)(hb + (size_t)row * 128);
#pragma unroll
        for (int step = 0; step < 4; ++step) {
            bf16x8 af = mrow[step * 4 + quad];
#pragma unroll
            for (int c = 0; c < 4; ++c) {
                bf16x8 bf = *(const bf16x8*)&sB[c * 16 + m][step * 32 + quad * 8];
                acc[c] = __builtin_amdgcn_mfma_f32_16x16x32_bf16(af, bf, acc[c], 0, 0, 0);
            }
        }
#pragma unroll
        for (int step = 0; step < 4; ++step) {
            bf16x8 af = hrow[step * 4 + quad];
#pragma unroll
            for (int c = 0; c < 4; ++c) {
                bf16x8 bf = *(const bf16x8*)&sB[c * 16 + m][128 + step * 32 + quad * 8];
                acc[c] = __builtin_amdgcn_mfma_f32_16x16x32_bf16(af, bf, acc[c], 0, 0, 0);
            }
        }
        // +bias
#pragma unroll
        for (int c = 0; c < 4; ++c) {
            float b = bl[c * 16 + m];
#pragma unroll
            for (int reg = 0; reg < 4; ++reg) acc[c][reg] += b;
        }
        // log_softmax per row (reg selects row; 16 lanes of this quad span cols, 4 tiles each)
        float lse[4];
#pragma unroll
        for (int reg = 0; reg < 4; ++reg) {
            float mx = fmaxf(fmaxf(acc[0][reg], acc[1][reg]), fmaxf(acc[2][reg], acc[3][reg]));
            for (int off = 8; off; off >>= 1) mx = fmaxf(mx, __shfl_xor(mx, off));
            float sm = expf(acc[0][reg] - mx) + expf(acc[1][reg] - mx) +
                       expf(acc[2][reg] - mx) + expf(acc[3][reg] - mx);
            for (int off = 8; off; off >>= 1) sm += __shfl_xor(sm, off);
            lse[reg] = mx + logf(sm);
        }
        // store f32 out (overwrites hb rows r0..r0+15 — all reads done above)
#pragma unroll
        for (int c = 0; c < 4; ++c) {
            int n = c * 16 + m;
#pragma unroll
            for (int reg = 0; reg < 4; ++reg) {
                int r = r0 + quad * 4 + reg;
                if (r < N) out[(size_t)r * 64 + n] = acc[c][reg] - lse[reg];
            }
        }
    }
}

extern "C" void kernel_launch(void* const* d_in, const int* in_sizes, int n_in,
                              void* d_out, int out_size, void* d_ws, size_t ws_size,
                              hipStream_t stream) {
    const float* x   = (const float*)d_in[0];
    const int*   ei  = (const int*)d_in[1];
    const float* Wl1 = (const float*)d_in[2];
    const float* bl1 = (const float*)d_in[3];
    const float* Wr1 = (const float*)d_in[4];
    const float* Wl2 = (const float*)d_in[5];
    const float* bl2 = (const float*)d_in[6];
    const float* Wr2 = (const float*)d_in[7];

    int N = in_sizes[0] / IN_C;
    int E = in_sizes[1] / 2;
    const int* src = ei;
    const int* dst = ei + E;

    // ws (32.8 MB): counts i32[N] | offs i32[N] | csr i32[E] | mean bf16[N*128]
    int* counts = (int*)d_ws;
    int* offs   = counts + N;
    int* csr    = offs + N;
    unsigned short* mean = (unsigned short*)(csr + E);
    // d_out (25.6 MB) sequentially holds: xb bf16[N*128] -> hb bf16[N*128] -> out f32[N*64]
    unsigned short* xb = (unsigned short*)d_out;
    unsigned short* hb = (unsigned short*)d_out;
    float* out = (float*)d_out;

    hipMemsetAsync(counts, 0, (size_t)N * sizeof(int), stream);

    int eblocks = (E + 255) / 256;
    hist_kernel<<<eblocks, 256, 0, stream>>>(dst, counts, E);
    scan_kernel<<<1, 1024, 0, stream>>>(counts, offs, N);
    bucket_kernel<<<eblocks, 256, 0, stream>>>(src, dst, offs, csr, E);

    // x -> bf16 (N*128 elems, exactly divisible by 256*8)
    convert_kernel<<<(N * IN_C) / (256 * 8), 256, 0, stream>>>(x, xb);

    int ntiles = (N + 63) / 64;
    int gblocks = (N * 16 + 255) / 256;  // 16 lanes/row

    // Layer 1
    agg_mean_kernel<<<gblocks, 256, 0, stream>>>(xb, counts, offs, csr, mean, N);
    gemm1_mfma_kernel<<<512, 256, 0, stream>>>(mean, x, Wl1, bl1, Wr1, hb, N, ntiles);

    // Layer 2
    agg_mean_kernel<<<gblocks, 256, 0, stream>>>(hb, counts, offs, csr, mean, N);
    gemm2_mfma_kernel<<<512, 256, 0, stream>>>(mean, hb, Wl2, bl2, Wr2, out, N, ntiles);
}

// Round 5
// 515.587 us; speedup vs baseline: 11.4894x; 1.2722x over previous
//
#include <hip/hip_runtime.h>
#include <cstdint>
#include <cstddef>

#define IN_C 128
#define HID_C 128
#define OUT_C 64

typedef __attribute__((ext_vector_type(8))) short bf16x8;
typedef __attribute__((ext_vector_type(8))) unsigned short u16x8;
typedef __attribute__((ext_vector_type(4))) float f32x4;

__device__ __forceinline__ float b2f(unsigned short s) {
    return __uint_as_float(((unsigned)s) << 16);
}
__device__ __forceinline__ unsigned short f2b(float f) {
    unsigned u = __float_as_uint(f);
    unsigned r = (u + 0x7fffu + ((u >> 16) & 1u)) >> 16;  // round-to-nearest-even
    return (unsigned short)r;
}

// ---- CSR build: histogram of dst ----
__global__ __launch_bounds__(256) void hist_kernel(
    const int* __restrict__ dst, int* __restrict__ counts, int E) {
    int e = blockIdx.x * 256 + threadIdx.x;
    if (e < E) atomicAdd(&counts[dst[e]], 1);
}

// ---- CSR build: bucket-start allocation (replaces serial scan; order-free) ----
// Wave-level inclusive scan of counts + one atomicAdd per wave on a global cursor.
__global__ __launch_bounds__(256) void alloc_kernel(
    const int* __restrict__ counts, int* __restrict__ offs,
    int* __restrict__ total, int N) {
    int i = blockIdx.x * 256 + threadIdx.x;
    int lane = threadIdx.x & 63;
    int c = (i < N) ? counts[i] : 0;
    int scan = c;
#pragma unroll
    for (int off = 1; off < 64; off <<= 1) {
        int v = __shfl_up(scan, off);
        if (lane >= off) scan += v;
    }
    int waveTot = __shfl(scan, 63);
    int base = 0;
    if (lane == 0) base = atomicAdd(total, waveTot);
    base = __shfl(base, 0);
    if (i < N) offs[i] = base + scan - c;  // exclusive prefix = bucket start
}

// ---- CSR build: scatter src ids into buckets. Advances offs -> bucket ends. ----
__global__ __launch_bounds__(256) void bucket_kernel(
    const int* __restrict__ src, const int* __restrict__ dst,
    int* __restrict__ offs, int* __restrict__ csr, int E) {
    int e = blockIdx.x * 256 + threadIdx.x;
    if (e < E) {
        int pos = atomicAdd(&offs[dst[e]], 1);
        csr[pos] = src[e];
    }
}

// ---- Convert x (f32) -> xb (bf16). N*128 = 12.8M elems = 6250 blocks * 256 thr * 8 ----
__global__ __launch_bounds__(256) void convert_kernel(
    const float* __restrict__ x, unsigned short* __restrict__ xb) {
    size_t i = ((size_t)blockIdx.x * 256 + threadIdx.x) * 8;
    float4 u = *(const float4*)(x + i);
    float4 v = *(const float4*)(x + i + 4);
    u16x8 o;
    o[0] = f2b(u.x); o[1] = f2b(u.y); o[2] = f2b(u.z); o[3] = f2b(u.w);
    o[4] = f2b(v.x); o[5] = f2b(v.y); o[6] = f2b(v.z); o[7] = f2b(v.w);
    *(u16x8*)(xb + i) = o;
}

// ---- Gather-mean: mean over CSR neighbors of bf16 features -> bf16 out ----
// 16 lanes per row, ushort8 (16B) per lane. No LDS, low VGPR -> high occupancy.
__global__ __launch_bounds__(256) void agg_mean_kernel(
    const unsigned short* __restrict__ feat, const int* __restrict__ counts,
    const int* __restrict__ ends, const int* __restrict__ csr,
    unsigned short* __restrict__ mean_out, int N) {
    int g = (blockIdx.x * 256 + threadIdx.x) >> 4;  // row id
    int q = threadIdx.x & 15;
    if (g >= N) return;
    int cnt = counts[g];
    int end = ends[g];
    int beg = end - cnt;
    float a0=0.f,a1=0.f,a2=0.f,a3=0.f,a4=0.f,a5=0.f,a6=0.f,a7=0.f;
    int i = beg;
    for (; i + 1 < end; i += 2) {
        int s0 = csr[i], s1 = csr[i + 1];
        u16x8 v0 = *(const u16x8*)(feat + (size_t)s0 * 128 + q * 8);
        u16x8 v1 = *(const u16x8*)(feat + (size_t)s1 * 128 + q * 8);
        a0 += b2f(v0[0]) + b2f(v1[0]); a1 += b2f(v0[1]) + b2f(v1[1]);
        a2 += b2f(v0[2]) + b2f(v1[2]); a3 += b2f(v0[3]) + b2f(v1[3]);
        a4 += b2f(v0[4]) + b2f(v1[4]); a5 += b2f(v0[5]) + b2f(v1[5]);
        a6 += b2f(v0[6]) + b2f(v1[6]); a7 += b2f(v0[7]) + b2f(v1[7]);
    }
    if (i < end) {
        int s0 = csr[i];
        u16x8 v0 = *(const u16x8*)(feat + (size_t)s0 * 128 + q * 8);
        a0 += b2f(v0[0]); a1 += b2f(v0[1]); a2 += b2f(v0[2]); a3 += b2f(v0[3]);
        a4 += b2f(v0[4]); a5 += b2f(v0[5]); a6 += b2f(v0[6]); a7 += b2f(v0[7]);
    }
    float invd = 1.0f / (float)max(cnt, 1);
    u16x8 o;
    o[0] = f2b(a0 * invd); o[1] = f2b(a1 * invd); o[2] = f2b(a2 * invd); o[3] = f2b(a3 * invd);
    o[4] = f2b(a4 * invd); o[5] = f2b(a5 * invd); o[6] = f2b(a6 * invd); o[7] = f2b(a7 * invd);
    *(u16x8*)(mean_out + (size_t)g * 128 + q * 8) = o;
}

// ---- Layer 1 MFMA GEMM: h(bf16) = relu([mean|x](N,256) @ [Wl;Wr](256,128) + bl) ----
// Block = 4 waves; wave handles 16 rows x 128 cols (8 col-tiles of 16x16, K = 8 steps of 32).
// A: steps 0-3 from mb (bf16), steps 4-7 from x (f32, converted in-register).
// B: bf16 in LDS as Bt[n][k], padded k-stride 260 (2-way bank aliasing only).
__global__ __launch_bounds__(256, 2) void gemm1_mfma_kernel(
    const unsigned short* __restrict__ mb, const float* __restrict__ x,
    const float* __restrict__ Wl, const float* __restrict__ bl,
    const float* __restrict__ Wr, unsigned short* __restrict__ hb,
    int N, int ntiles) {
    __shared__ unsigned short sB[128][260];  // 66,560 B
    int tid = threadIdx.x;
    for (int i = tid; i < 128 * 128; i += 256) {
        int k = i >> 7, n = i & 127;
        sB[n][k] = f2b(Wl[i]);        // Wl[k][n]
        sB[n][128 + k] = f2b(Wr[i]);  // Wr[k][n]
    }
    __syncthreads();
    int wave = tid >> 6, lane = tid & 63;
    int quad = lane >> 4, m = lane & 15;
    for (int tile = blockIdx.x; tile < ntiles; tile += gridDim.x) {
        int r0 = tile * 64 + wave * 16;
        int row = min(r0 + m, N - 1);  // A-load row for this lane (clamped)
        f32x4 acc[8];
#pragma unroll
        for (int c = 0; c < 8; ++c) acc[c] = {0.f, 0.f, 0.f, 0.f};
        // K-steps 0..3: A = mean (bf16)
        const bf16x8* mrow = (const bf16x8*)(mb + (size_t)row * 128);
#pragma unroll
        for (int step = 0; step < 4; ++step) {
            bf16x8 af = mrow[step * 4 + quad];
#pragma unroll
            for (int c = 0; c < 8; ++c) {
                bf16x8 bf = *(const bf16x8*)&sB[c * 16 + m][step * 32 + quad * 8];
                acc[c] = __builtin_amdgcn_mfma_f32_16x16x32_bf16(af, bf, acc[c], 0, 0, 0);
            }
        }
        // K-steps 4..7: A = x (f32 -> bf16 in-register)
        const float* xrow = x + (size_t)row * 128;
#pragma unroll
        for (int step = 0; step < 4; ++step) {
            int k0 = step * 32 + quad * 8;
            float4 u = *(const float4*)(xrow + k0);
            float4 v = *(const float4*)(xrow + k0 + 4);
            bf16x8 af;
            af[0] = (short)f2b(u.x); af[1] = (short)f2b(u.y);
            af[2] = (short)f2b(u.z); af[3] = (short)f2b(u.w);
            af[4] = (short)f2b(v.x); af[5] = (short)f2b(v.y);
            af[6] = (short)f2b(v.z); af[7] = (short)f2b(v.w);
#pragma unroll
            for (int c = 0; c < 8; ++c) {
                bf16x8 bf = *(const bf16x8*)&sB[c * 16 + m][128 + step * 32 + quad * 8];
                acc[c] = __builtin_amdgcn_mfma_f32_16x16x32_bf16(af, bf, acc[c], 0, 0, 0);
            }
        }
        // Epilogue: +bias, relu, bf16 store. C/D: col = c*16 + (lane&15), row = r0 + quad*4 + reg
#pragma unroll
        for (int c = 0; c < 8; ++c) {
            int n = c * 16 + m;
            float b = bl[n];
#pragma unroll
            for (int reg = 0; reg < 4; ++reg) {
                int r = r0 + quad * 4 + reg;
                if (r < N) hb[(size_t)r * 128 + n] = f2b(fmaxf(acc[c][reg] + b, 0.f));
            }
        }
    }
}

// ---- Layer 2 MFMA GEMM + log_softmax: out(f32) = lsm([mean2|h](N,256) @ [Wl2;Wr2](256,64) + bl2) ----
// Wave: 16 rows x 64 cols (4 col-tiles). h (bf16) ALIASES out rows byte-for-byte
// (128*2B == 64*4B); all in-wave h reads precede the out store.
__global__ __launch_bounds__(256, 2) void gemm2_mfma_kernel(
    const unsigned short* __restrict__ mb, const unsigned short* __restrict__ hb,
    const float* __restrict__ Wl, const float* __restrict__ bl,
    const float* __restrict__ Wr, float* __restrict__ out,
    int N, int ntiles) {
    __shared__ unsigned short sB[64][260];  // 33,280 B
    int tid = threadIdx.x;
    for (int i = tid; i < 128 * 64; i += 256) {
        int k = i >> 6, n = i & 63;
        sB[n][k] = f2b(Wl[i]);        // Wl2[k][n]
        sB[n][128 + k] = f2b(Wr[i]);  // Wr2[k][n]
    }
    __syncthreads();
    int wave = tid >> 6, lane = tid & 63;
    int quad = lane >> 4, m = lane & 15;
    for (int tile = blockIdx.x; tile < ntiles; tile += gridDim.x) {
        int r0 = tile * 64 + wave * 16;
        int row = min(r0 + m, N - 1);
        f32x4 acc[4];
#pragma unroll
        for (int c = 0; c < 4; ++c) acc[c] = {0.f, 0.f, 0.f, 0.f};
        const bf16x8* mrow = (const bf16x8*)(mb + (size_t)row * 128);
        const bf16x8* hrow = (const bf16x8*)(hb + (size_t)row * 128);
#pragma unroll
        for (int step = 0; step < 4; ++step) {
            bf16x8 af = mrow[step * 4 + quad];
#pragma unroll
            for (int c = 0; c < 4; ++c) {
                bf16x8 bf = *(const bf16x8*)&sB[c * 16 + m][step * 32 + quad * 8];
                acc[c] = __builtin_amdgcn_mfma_f32_16x16x32_bf16(af, bf, acc[c], 0, 0, 0);
            }
        }
#pragma unroll
        for (int step = 0; step < 4; ++step) {
            bf16x8 af = hrow[step * 4 + quad];
#pragma unroll
            for (int c = 0; c < 4; ++c) {
                bf16x8 bf = *(const bf16x8*)&sB[c * 16 + m][128 + step * 32 + quad * 8];
                acc[c] = __builtin_amdgcn_mfma_f32_16x16x32_bf16(af, bf, acc[c], 0, 0, 0);
            }
        }
        // +bias
#pragma unroll
        for (int c = 0; c < 4; ++c) {
            float b = bl[c * 16 + m];
#pragma unroll
            for (int reg = 0; reg < 4; ++reg) acc[c][reg] += b;
        }
        // log_softmax per row (reg selects row; 16 lanes of this quad span cols, 4 tiles each)
        float lse[4];
#pragma unroll
        for (int reg = 0; reg < 4; ++reg) {
            float mx = fmaxf(fmaxf(acc[0][reg], acc[1][reg]), fmaxf(acc[2][reg], acc[3][reg]));
            for (int off = 8; off; off >>= 1) mx = fmaxf(mx, __shfl_xor(mx, off));
            float sm = expf(acc[0][reg] - mx) + expf(acc[1][reg] - mx) +
                       expf(acc[2][reg] - mx) + expf(acc[3][reg] - mx);
            for (int off = 8; off; off >>= 1) sm += __shfl_xor(sm, off);
            lse[reg] = mx + logf(sm);
        }
        // store f32 out (overwrites hb rows r0..r0+15 — all reads done above)
#pragma unroll
        for (int c = 0; c < 4; ++c) {
            int n = c * 16 + m;
#pragma unroll
            for (int reg = 0; reg < 4; ++reg) {
                int r = r0 + quad * 4 + reg;
                if (r < N) out[(size_t)r * 64 + n] = acc[c][reg] - lse[reg];
            }
        }
    }
}

extern "C" void kernel_launch(void* const* d_in, const int* in_sizes, int n_in,
                              void* d_out, int out_size, void* d_ws, size_t ws_size,
                              hipStream_t stream) {
    const float* x   = (const float*)d_in[0];
    const int*   ei  = (const int*)d_in[1];
    const float* Wl1 = (const float*)d_in[2];
    const float* bl1 = (const float*)d_in[3];
    const float* Wr1 = (const float*)d_in[4];
    const float* Wl2 = (const float*)d_in[5];
    const float* bl2 = (const float*)d_in[6];
    const float* Wr2 = (const float*)d_in[7];

    int N = in_sizes[0] / IN_C;
    int E = in_sizes[1] / 2;
    const int* src = ei;
    const int* dst = ei + E;

    // ws (32.8 MB + 16 B): counts i32[N] | offs i32[N] | csr i32[E] | mean bf16[N*128] | total i32[4]
    int* counts = (int*)d_ws;
    int* offs   = counts + N;
    int* csr    = offs + N;
    unsigned short* mean = (unsigned short*)(csr + E);
    int* total  = (int*)(mean + (size_t)N * 128);
    // d_out (25.6 MB) sequentially holds: xb bf16[N*128] -> hb bf16[N*128] -> out f32[N*64]
    unsigned short* xb = (unsigned short*)d_out;
    unsigned short* hb = (unsigned short*)d_out;
    float* out = (float*)d_out;

    hipMemsetAsync(counts, 0, (size_t)N * sizeof(int), stream);
    hipMemsetAsync(total, 0, sizeof(int), stream);

    int eblocks = (E + 255) / 256;
    hist_kernel<<<eblocks, 256, 0, stream>>>(dst, counts, E);
    alloc_kernel<<<(N + 255) / 256, 256, 0, stream>>>(counts, offs, total, N);
    bucket_kernel<<<eblocks, 256, 0, stream>>>(src, dst, offs, csr, E);

    // x -> bf16 (N*128 elems, exactly divisible by 256*8)
    convert_kernel<<<(N * IN_C) / (256 * 8), 256, 0, stream>>>(x, xb);

    int ntiles = (N + 63) / 64;
    int gblocks = (N * 16 + 255) / 256;  // 16 lanes/row

    // Layer 1
    agg_mean_kernel<<<gblocks, 256, 0, stream>>>(xb, counts, offs, csr, mean, N);
    gemm1_mfma_kernel<<<512, 256, 0, stream>>>(mean, x, Wl1, bl1, Wr1, hb, N, ntiles);

    // Layer 2
    agg_mean_kernel<<<gblocks, 256, 0, stream>>>(hb, counts, offs, csr, mean, N);
    gemm2_mfma_kernel<<<512, 256, 0, stream>>>(mean, hb, Wl2, bl2, Wr2, out, N, ntiles);
}

// Round 6
// 502.721 us; speedup vs baseline: 11.7835x; 1.0256x over previous
//
#include <hip/hip_runtime.h>
#include <cstdint>
#include <cstddef>

#define IN_C 128
#define HID_C 128
#define OUT_C 64

typedef __attribute__((ext_vector_type(8))) short bf16x8;
typedef __attribute__((ext_vector_type(8))) unsigned short u16x8;
typedef __attribute__((ext_vector_type(4))) float f32x4;

__device__ __forceinline__ float b2f(unsigned short s) {
    return __uint_as_float(((unsigned)s) << 16);
}
__device__ __forceinline__ unsigned short f2b(float f) {
    unsigned u = __float_as_uint(f);
    unsigned r = (u + 0x7fffu + ((u >> 16) & 1u)) >> 16;  // round-to-nearest-even
    return (unsigned short)r;
}

// ---- CSR build: histogram of dst ----
__global__ __launch_bounds__(256) void hist_kernel(
    const int* __restrict__ dst, int* __restrict__ counts, int E) {
    int e = blockIdx.x * 256 + threadIdx.x;
    if (e < E) atomicAdd(&counts[dst[e]], 1);
}

// ---- CSR build: bucket-start allocation (order-free) ----
__global__ __launch_bounds__(256) void alloc_kernel(
    const int* __restrict__ counts, int* __restrict__ offs,
    int* __restrict__ total, int N) {
    int i = blockIdx.x * 256 + threadIdx.x;
    int lane = threadIdx.x & 63;
    int c = (i < N) ? counts[i] : 0;
    int scan = c;
#pragma unroll
    for (int off = 1; off < 64; off <<= 1) {
        int v = __shfl_up(scan, off);
        if (lane >= off) scan += v;
    }
    int waveTot = __shfl(scan, 63);
    int base = 0;
    if (lane == 0) base = atomicAdd(total, waveTot);
    base = __shfl(base, 0);
    if (i < N) offs[i] = base + scan - c;  // exclusive prefix = bucket start
}

// ---- CSR build: scatter src ids into buckets. Advances offs -> bucket ends. ----
__global__ __launch_bounds__(256) void bucket_kernel(
    const int* __restrict__ src, const int* __restrict__ dst,
    int* __restrict__ offs, int* __restrict__ csr, int E) {
    int e = blockIdx.x * 256 + threadIdx.x;
    if (e < E) {
        int pos = atomicAdd(&offs[dst[e]], 1);
        csr[pos] = src[e];
    }
}

// ---- Convert x (f32) -> xb (bf16) ----
__global__ __launch_bounds__(256) void convert_kernel(
    const float* __restrict__ x, unsigned short* __restrict__ xb) {
    size_t i = ((size_t)blockIdx.x * 256 + threadIdx.x) * 8;
    float4 u = *(const float4*)(x + i);
    float4 v = *(const float4*)(x + i + 4);
    u16x8 o;
    o[0] = f2b(u.x); o[1] = f2b(u.y); o[2] = f2b(u.z); o[3] = f2b(u.w);
    o[4] = f2b(v.x); o[5] = f2b(v.y); o[6] = f2b(v.z); o[7] = f2b(v.w);
    *(u16x8*)(xb + i) = o;
}

// ---- Gather-mean: mean over CSR neighbors of bf16 features -> bf16 out ----
__global__ __launch_bounds__(256) void agg_mean_kernel(
    const unsigned short* __restrict__ feat, const int* __restrict__ counts,
    const int* __restrict__ ends, const int* __restrict__ csr,
    unsigned short* __restrict__ mean_out, int N) {
    int g = (blockIdx.x * 256 + threadIdx.x) >> 4;  // row id
    int q = threadIdx.x & 15;
    if (g >= N) return;
    int cnt = counts[g];
    int end = ends[g];
    int beg = end - cnt;
    float a0=0.f,a1=0.f,a2=0.f,a3=0.f,a4=0.f,a5=0.f,a6=0.f,a7=0.f;
    int i = beg;
    for (; i + 1 < end; i += 2) {
        int s0 = csr[i], s1 = csr[i + 1];
        u16x8 v0 = *(const u16x8*)(feat + (size_t)s0 * 128 + q * 8);
        u16x8 v1 = *(const u16x8*)(feat + (size_t)s1 * 128 + q * 8);
        a0 += b2f(v0[0]) + b2f(v1[0]); a1 += b2f(v0[1]) + b2f(v1[1]);
        a2 += b2f(v0[2]) + b2f(v1[2]); a3 += b2f(v0[3]) + b2f(v1[3]);
        a4 += b2f(v0[4]) + b2f(v1[4]); a5 += b2f(v0[5]) + b2f(v1[5]);
        a6 += b2f(v0[6]) + b2f(v1[6]); a7 += b2f(v0[7]) + b2f(v1[7]);
    }
    if (i < end) {
        int s0 = csr[i];
        u16x8 v0 = *(const u16x8*)(feat + (size_t)s0 * 128 + q * 8);
        a0 += b2f(v0[0]); a1 += b2f(v0[1]); a2 += b2f(v0[2]); a3 += b2f(v0[3]);
        a4 += b2f(v0[4]); a5 += b2f(v0[5]); a6 += b2f(v0[6]); a7 += b2f(v0[7]);
    }
    float invd = 1.0f / (float)max(cnt, 1);
    u16x8 o;
    o[0] = f2b(a0 * invd); o[1] = f2b(a1 * invd); o[2] = f2b(a2 * invd); o[3] = f2b(a3 * invd);
    o[4] = f2b(a4 * invd); o[5] = f2b(a5 * invd); o[6] = f2b(a6 * invd); o[7] = f2b(a7 * invd);
    *(u16x8*)(mean_out + (size_t)g * 128 + q * 8) = o;
}

// ---- Layer 1 MFMA GEMM: h(bf16) = relu([mean|xb](N,256) @ [Wl;Wr](256,128) + bl) ----
// Operands SWAPPED (D^T): mfma(bf, af) -> lane owns row r0+(lane&15), channels
// c*16 + quad*4 + reg -> coalesced ushort4 stores.
// xb ALIASES hb (d_out): each wave reads exactly the rows it later writes; stores
// are dataflow-dependent on the reads. Clamped row-(N-1) readers never store.
__global__ __launch_bounds__(256, 2) void gemm1_mfma_kernel(
    const unsigned short* __restrict__ mb, const unsigned short* __restrict__ xb,
    const float* __restrict__ Wl, const float* __restrict__ bl,
    const float* __restrict__ Wr, unsigned short* __restrict__ hb,
    int N, int ntiles) {
    __shared__ unsigned short sB[128][260];  // 66,560 B
    int tid = threadIdx.x;
    for (int i = tid; i < 128 * 128; i += 256) {
        int k = i >> 7, n = i & 127;
        sB[n][k] = f2b(Wl[i]);        // Wl[k][n]
        sB[n][128 + k] = f2b(Wr[i]);  // Wr[k][n]
    }
    __syncthreads();
    int wave = tid >> 6, lane = tid & 63;
    int quad = lane >> 4, m = lane & 15;
    for (int tile = blockIdx.x; tile < ntiles; tile += gridDim.x) {
        int r0 = tile * 64 + wave * 16;
        int row = min(r0 + m, N - 1);  // A-load row for this lane (clamped)
        f32x4 acc[8];
#pragma unroll
        for (int c = 0; c < 8; ++c) acc[c] = {0.f, 0.f, 0.f, 0.f};
        const bf16x8* mrow = (const bf16x8*)(mb + (size_t)row * 128);
        const bf16x8* xrow = (const bf16x8*)(xb + (size_t)row * 128);
#pragma unroll
        for (int step = 0; step < 4; ++step) {
            bf16x8 af = mrow[step * 4 + quad];
#pragma unroll
            for (int c = 0; c < 8; ++c) {
                bf16x8 bf = *(const bf16x8*)&sB[c * 16 + m][step * 32 + quad * 8];
                acc[c] = __builtin_amdgcn_mfma_f32_16x16x32_bf16(bf, af, acc[c], 0, 0, 0);
            }
        }
#pragma unroll
        for (int step = 0; step < 4; ++step) {
            bf16x8 af = xrow[step * 4 + quad];
#pragma unroll
            for (int c = 0; c < 8; ++c) {
                bf16x8 bf = *(const bf16x8*)&sB[c * 16 + m][128 + step * 32 + quad * 8];
                acc[c] = __builtin_amdgcn_mfma_f32_16x16x32_bf16(bf, af, acc[c], 0, 0, 0);
            }
        }
        // Epilogue (D^T): lane owns row r0+m, channels c*16+quad*4+{0..3}
        int r = r0 + m;
        if (r < N) {
#pragma unroll
            for (int c = 0; c < 8; ++c) {
                float4 b4 = *(const float4*)&bl[c * 16 + quad * 4];
                ushort4 o;
                o.x = f2b(fmaxf(acc[c][0] + b4.x, 0.f));
                o.y = f2b(fmaxf(acc[c][1] + b4.y, 0.f));
                o.z = f2b(fmaxf(acc[c][2] + b4.z, 0.f));
                o.w = f2b(fmaxf(acc[c][3] + b4.w, 0.f));
                *(ushort4*)&hb[(size_t)r * 128 + c * 16 + quad * 4] = o;
            }
        }
    }
}

// ---- Layer 2 MFMA GEMM + log_softmax: out(f32) = lsm([mean2|h](N,256) @ [Wl2;Wr2](256,64) + bl2) ----
// Swapped operands: lane owns row r0+m, channels c*16+quad*4+reg (16 of 64).
// Softmax reduces across the 4 lanes (quads) sharing a row: shfl_xor 16, 32.
// h (bf16) ALIASES out rows byte-for-byte; reads precede the dependent store.
__global__ __launch_bounds__(256, 2) void gemm2_mfma_kernel(
    const unsigned short* __restrict__ mb, const unsigned short* __restrict__ hb,
    const float* __restrict__ Wl, const float* __restrict__ bl,
    const float* __restrict__ Wr, float* __restrict__ out,
    int N, int ntiles) {
    __shared__ unsigned short sB[64][260];  // 33,280 B
    int tid = threadIdx.x;
    for (int i = tid; i < 128 * 64; i += 256) {
        int k = i >> 6, n = i & 63;
        sB[n][k] = f2b(Wl[i]);        // Wl2[k][n]
        sB[n][128 + k] = f2b(Wr[i]);  // Wr2[k][n]
    }
    __syncthreads();
    int wave = tid >> 6, lane = tid & 63;
    int quad = lane >> 4, m = lane & 15;
    for (int tile = blockIdx.x; tile < ntiles; tile += gridDim.x) {
        int r0 = tile * 64 + wave * 16;
        int row = min(r0 + m, N - 1);
        f32x4 acc[4];
#pragma unroll
        for (int c = 0; c < 4; ++c) acc[c] = {0.f, 0.f, 0.f, 0.f};
        const bf16x8* mrow = (const bf16x8*)(mb + (size_t)row * 128);
        const bf16x8* hrow = (const bf16x8*)(hb + (size_t)row * 128);
#pragma unroll
        for (int step = 0; step < 4; ++step) {
            bf16x8 af = mrow[step * 4 + quad];
#pragma unroll
            for (int c = 0; c < 4; ++c) {
                bf16x8 bf = *(const bf16x8*)&sB[c * 16 + m][step * 32 + quad * 8];
                acc[c] = __builtin_amdgcn_mfma_f32_16x16x32_bf16(bf, af, acc[c], 0, 0, 0);
            }
        }
#pragma unroll
        for (int step = 0; step < 4; ++step) {
            bf16x8 af = hrow[step * 4 + quad];
#pragma unroll
            for (int c = 0; c < 4; ++c) {
                bf16x8 bf = *(const bf16x8*)&sB[c * 16 + m][128 + step * 32 + quad * 8];
                acc[c] = __builtin_amdgcn_mfma_f32_16x16x32_bf16(bf, af, acc[c], 0, 0, 0);
            }
        }
        // +bias (channel = c*16 + quad*4 + reg)
#pragma unroll
        for (int c = 0; c < 4; ++c) {
            float4 b4 = *(const float4*)&bl[c * 16 + quad * 4];
            acc[c][0] += b4.x; acc[c][1] += b4.y; acc[c][2] += b4.z; acc[c][3] += b4.w;
        }
        // log_softmax: row r0+m spans lanes {m, m+16, m+32, m+48}
        float mx = -1e30f;
#pragma unroll
        for (int c = 0; c < 4; ++c)
            mx = fmaxf(mx, fmaxf(fmaxf(acc[c][0], acc[c][1]), fmaxf(acc[c][2], acc[c][3])));
        mx = fmaxf(mx, __shfl_xor(mx, 16));
        mx = fmaxf(mx, __shfl_xor(mx, 32));
        float sm = 0.f;
#pragma unroll
        for (int c = 0; c < 4; ++c)
            sm += expf(acc[c][0] - mx) + expf(acc[c][1] - mx) +
                  expf(acc[c][2] - mx) + expf(acc[c][3] - mx);
        sm += __shfl_xor(sm, 16);
        sm += __shfl_xor(sm, 32);
        float lse = mx + logf(sm);
        int r = r0 + m;
        if (r < N) {
#pragma unroll
            for (int c = 0; c < 4; ++c) {
                float4 o = {acc[c][0] - lse, acc[c][1] - lse,
                            acc[c][2] - lse, acc[c][3] - lse};
                *(float4*)&out[(size_t)r * 64 + c * 16 + quad * 4] = o;
            }
        }
    }
}

extern "C" void kernel_launch(void* const* d_in, const int* in_sizes, int n_in,
                              void* d_out, int out_size, void* d_ws, size_t ws_size,
                              hipStream_t stream) {
    const float* x   = (const float*)d_in[0];
    const int*   ei  = (const int*)d_in[1];
    const float* Wl1 = (const float*)d_in[2];
    const float* bl1 = (const float*)d_in[3];
    const float* Wr1 = (const float*)d_in[4];
    const float* Wl2 = (const float*)d_in[5];
    const float* bl2 = (const float*)d_in[6];
    const float* Wr2 = (const float*)d_in[7];

    int N = in_sizes[0] / IN_C;
    int E = in_sizes[1] / 2;
    const int* src = ei;
    const int* dst = ei + E;

    // ws (32.8 MB + 16 B): counts i32[N] | offs i32[N] | csr i32[E] | mean bf16[N*128] | total i32[4]
    int* counts = (int*)d_ws;
    int* offs   = counts + N;
    int* csr    = offs + N;
    unsigned short* mean = (unsigned short*)(csr + E);
    int* total  = (int*)(mean + (size_t)N * 128);
    // d_out (25.6 MB) sequentially holds: xb bf16[N*128] -> hb bf16[N*128] -> out f32[N*64]
    unsigned short* xb = (unsigned short*)d_out;
    unsigned short* hb = (unsigned short*)d_out;
    float* out = (float*)d_out;

    hipMemsetAsync(counts, 0, (size_t)N * sizeof(int), stream);
    hipMemsetAsync(total, 0, sizeof(int), stream);

    int eblocks = (E + 255) / 256;
    hist_kernel<<<eblocks, 256, 0, stream>>>(dst, counts, E);
    alloc_kernel<<<(N + 255) / 256, 256, 0, stream>>>(counts, offs, total, N);
    bucket_kernel<<<eblocks, 256, 0, stream>>>(src, dst, offs, csr, E);

    // x -> bf16
    convert_kernel<<<(N * IN_C) / (256 * 8), 256, 0, stream>>>(x, xb);

    int ntiles = (N + 63) / 64;
    int gblocks = (N * 16 + 255) / 256;  // 16 lanes/row

    // Layer 1
    agg_mean_kernel<<<gblocks, 256, 0, stream>>>(xb, counts, offs, csr, mean, N);
    gemm1_mfma_kernel<<<512, 256, 0, stream>>>(mean, xb, Wl1, bl1, Wr1, hb, N, ntiles);

    // Layer 2
    agg_mean_kernel<<<gblocks, 256, 0, stream>>>(hb, counts, offs, csr, mean, N);
    gemm2_mfma_kernel<<<512, 256, 0, stream>>>(mean, hb, Wl2, bl2, Wr2, out, N, ntiles);
}

// Round 7
// 460.452 us; speedup vs baseline: 12.8652x; 1.0918x over previous
//
#include <hip/hip_runtime.h>
#include <cstdint>
#include <cstddef>

#define IN_C 128
#define HID_C 128
#define OUT_C 64

typedef __attribute__((ext_vector_type(8))) short bf16x8;
typedef __attribute__((ext_vector_type(8))) unsigned short u16x8;
typedef __attribute__((ext_vector_type(4))) float f32x4;

__device__ __forceinline__ float b2f(unsigned short s) {
    return __uint_as_float(((unsigned)s) << 16);
}
__device__ __forceinline__ unsigned short f2b(float f) {
    unsigned u = __float_as_uint(f);
    unsigned r = (u + 0x7fffu + ((u >> 16) & 1u)) >> 16;  // round-to-nearest-even
    return (unsigned short)r;
}

// ---- CSR build: histogram of dst ----
__global__ __launch_bounds__(256) void hist_kernel(
    const int* __restrict__ dst, int* __restrict__ counts, int E) {
    int e = blockIdx.x * 256 + threadIdx.x;
    if (e < E) atomicAdd(&counts[dst[e]], 1);
}

// ---- CSR build: bucket-start allocation (order-free) ----
__global__ __launch_bounds__(256) void alloc_kernel(
    const int* __restrict__ counts, int* __restrict__ offs,
    int* __restrict__ total, int N) {
    int i = blockIdx.x * 256 + threadIdx.x;
    int lane = threadIdx.x & 63;
    int c = (i < N) ? counts[i] : 0;
    int scan = c;
#pragma unroll
    for (int off = 1; off < 64; off <<= 1) {
        int v = __shfl_up(scan, off);
        if (lane >= off) scan += v;
    }
    int waveTot = __shfl(scan, 63);
    int base = 0;
    if (lane == 0) base = atomicAdd(total, waveTot);
    base = __shfl(base, 0);
    if (i < N) offs[i] = base + scan - c;  // exclusive prefix = bucket start
}

// ---- CSR build: XCD-range-partitioned scatter. Advances offs -> bucket ends. ----
// Group g = blockIdx&7 handles dst in [g*grpSize, (g+1)*grpSize): csr slice
// ~800 KB fits one XCD's 4 MB L2 (blockIdx%8 ~ XCD round-robin heuristic;
// correctness holds for ANY mapping — all (chunk,group) pairs are launched).
#define BK_CHUNK 1024
__global__ __launch_bounds__(256) void bucket_kernel(
    const int* __restrict__ src, const int* __restrict__ dst,
    int* __restrict__ offs, int* __restrict__ csr, int E, int N) {
    int grp = blockIdx.x & 7;
    int chunk = blockIdx.x >> 3;
    int grpSize = (N + 7) >> 3;
    int lo = grp * grpSize;
    int hi = min(lo + grpSize, N);
#pragma unroll
    for (int i = 0; i < BK_CHUNK / 256; ++i) {
        int e = chunk * BK_CHUNK + i * 256 + threadIdx.x;
        if (e < E) {
            int d = dst[e];
            if (d >= lo && d < hi) {
                int pos = atomicAdd(&offs[d], 1);
                csr[pos] = src[e];
            }
        }
    }
}

// ---- Convert x (f32) -> xb (bf16) ----
__global__ __launch_bounds__(256) void convert_kernel(
    const float* __restrict__ x, unsigned short* __restrict__ xb) {
    size_t i = ((size_t)blockIdx.x * 256 + threadIdx.x) * 8;
    float4 u = *(const float4*)(x + i);
    float4 v = *(const float4*)(x + i + 4);
    u16x8 o;
    o[0] = f2b(u.x); o[1] = f2b(u.y); o[2] = f2b(u.z); o[3] = f2b(u.w);
    o[4] = f2b(v.x); o[5] = f2b(v.y); o[6] = f2b(v.z); o[7] = f2b(v.w);
    *(u16x8*)(xb + i) = o;
}

// ---- Gather-mean: mean over CSR neighbors of bf16 features -> bf16 out ----
__global__ __launch_bounds__(256) void agg_mean_kernel(
    const unsigned short* __restrict__ feat, const int* __restrict__ counts,
    const int* __restrict__ ends, const int* __restrict__ csr,
    unsigned short* __restrict__ mean_out, int N) {
    int g = (blockIdx.x * 256 + threadIdx.x) >> 4;  // row id
    int q = threadIdx.x & 15;
    if (g >= N) return;
    int cnt = counts[g];
    int end = ends[g];
    int beg = end - cnt;
    float a0=0.f,a1=0.f,a2=0.f,a3=0.f,a4=0.f,a5=0.f,a6=0.f,a7=0.f;
    int i = beg;
    for (; i + 1 < end; i += 2) {
        int s0 = csr[i], s1 = csr[i + 1];
        u16x8 v0 = *(const u16x8*)(feat + (size_t)s0 * 128 + q * 8);
        u16x8 v1 = *(const u16x8*)(feat + (size_t)s1 * 128 + q * 8);
        a0 += b2f(v0[0]) + b2f(v1[0]); a1 += b2f(v0[1]) + b2f(v1[1]);
        a2 += b2f(v0[2]) + b2f(v1[2]); a3 += b2f(v0[3]) + b2f(v1[3]);
        a4 += b2f(v0[4]) + b2f(v1[4]); a5 += b2f(v0[5]) + b2f(v1[5]);
        a6 += b2f(v0[6]) + b2f(v1[6]); a7 += b2f(v0[7]) + b2f(v1[7]);
    }
    if (i < end) {
        int s0 = csr[i];
        u16x8 v0 = *(const u16x8*)(feat + (size_t)s0 * 128 + q * 8);
        a0 += b2f(v0[0]); a1 += b2f(v0[1]); a2 += b2f(v0[2]); a3 += b2f(v0[3]);
        a4 += b2f(v0[4]); a5 += b2f(v0[5]); a6 += b2f(v0[6]); a7 += b2f(v0[7]);
    }
    float invd = 1.0f / (float)max(cnt, 1);
    u16x8 o;
    o[0] = f2b(a0 * invd); o[1] = f2b(a1 * invd); o[2] = f2b(a2 * invd); o[3] = f2b(a3 * invd);
    o[4] = f2b(a4 * invd); o[5] = f2b(a5 * invd); o[6] = f2b(a6 * invd); o[7] = f2b(a7 * invd);
    *(u16x8*)(mean_out + (size_t)g * 128 + q * 8) = o;
}

// ---- Layer 1 MFMA GEMM: h(bf16) = relu([mean|xb](N,256) @ [Wl;Wr](256,128) + bl) ----
// Operands SWAPPED (D^T): mfma(bf, af) -> lane owns row r0+(lane&15), channels
// c*16 + quad*4 + reg -> coalesced ushort4 stores.
// xb ALIASES hb (d_out): each wave reads exactly the rows it later writes; stores
// are dataflow-dependent on the reads. Clamped row-(N-1) readers never store.
__global__ __launch_bounds__(256, 2) void gemm1_mfma_kernel(
    const unsigned short* __restrict__ mb, const unsigned short* __restrict__ xb,
    const float* __restrict__ Wl, const float* __restrict__ bl,
    const float* __restrict__ Wr, unsigned short* __restrict__ hb,
    int N, int ntiles) {
    __shared__ unsigned short sB[128][260];  // 66,560 B
    int tid = threadIdx.x;
    for (int i = tid; i < 128 * 128; i += 256) {
        int k = i >> 7, n = i & 127;
        sB[n][k] = f2b(Wl[i]);        // Wl[k][n]
        sB[n][128 + k] = f2b(Wr[i]);  // Wr[k][n]
    }
    __syncthreads();
    int wave = tid >> 6, lane = tid & 63;
    int quad = lane >> 4, m = lane & 15;
    for (int tile = blockIdx.x; tile < ntiles; tile += gridDim.x) {
        int r0 = tile * 64 + wave * 16;
        int row = min(r0 + m, N - 1);  // A-load row for this lane (clamped)
        f32x4 acc[8];
#pragma unroll
        for (int c = 0; c < 8; ++c) acc[c] = {0.f, 0.f, 0.f, 0.f};
        const bf16x8* mrow = (const bf16x8*)(mb + (size_t)row * 128);
        const bf16x8* xrow = (const bf16x8*)(xb + (size_t)row * 128);
#pragma unroll
        for (int step = 0; step < 4; ++step) {
            bf16x8 af = mrow[step * 4 + quad];
#pragma unroll
            for (int c = 0; c < 8; ++c) {
                bf16x8 bf = *(const bf16x8*)&sB[c * 16 + m][step * 32 + quad * 8];
                acc[c] = __builtin_amdgcn_mfma_f32_16x16x32_bf16(bf, af, acc[c], 0, 0, 0);
            }
        }
#pragma unroll
        for (int step = 0; step < 4; ++step) {
            bf16x8 af = xrow[step * 4 + quad];
#pragma unroll
            for (int c = 0; c < 8; ++c) {
                bf16x8 bf = *(const bf16x8*)&sB[c * 16 + m][128 + step * 32 + quad * 8];
                acc[c] = __builtin_amdgcn_mfma_f32_16x16x32_bf16(bf, af, acc[c], 0, 0, 0);
            }
        }
        // Epilogue (D^T): lane owns row r0+m, channels c*16+quad*4+{0..3}
        int r = r0 + m;
        if (r < N) {
#pragma unroll
            for (int c = 0; c < 8; ++c) {
                float4 b4 = *(const float4*)&bl[c * 16 + quad * 4];
                ushort4 o;
                o.x = f2b(fmaxf(acc[c][0] + b4.x, 0.f));
                o.y = f2b(fmaxf(acc[c][1] + b4.y, 0.f));
                o.z = f2b(fmaxf(acc[c][2] + b4.z, 0.f));
                o.w = f2b(fmaxf(acc[c][3] + b4.w, 0.f));
                *(ushort4*)&hb[(size_t)r * 128 + c * 16 + quad * 4] = o;
            }
        }
    }
}

// ---- Layer 2 MFMA GEMM + log_softmax: out(f32) = lsm([mean2|h](N,256) @ [Wl2;Wr2](256,64) + bl2) ----
// Swapped operands: lane owns row r0+m, channels c*16+quad*4+reg (16 of 64).
// Softmax reduces across the 4 lanes (quads) sharing a row: shfl_xor 16, 32.
// h (bf16) ALIASES out rows byte-for-byte; reads precede the dependent store.
__global__ __launch_bounds__(256, 2) void gemm2_mfma_kernel(
    const unsigned short* __restrict__ mb, const unsigned short* __restrict__ hb,
    const float* __restrict__ Wl, const float* __restrict__ bl,
    const float* __restrict__ Wr, float* __restrict__ out,
    int N, int ntiles) {
    __shared__ unsigned short sB[64][260];  // 33,280 B
    int tid = threadIdx.x;
    for (int i = tid; i < 128 * 64; i += 256) {
        int k = i >> 6, n = i & 63;
        sB[n][k] = f2b(Wl[i]);        // Wl2[k][n]
        sB[n][128 + k] = f2b(Wr[i]);  // Wr2[k][n]
    }
    __syncthreads();
    int wave = tid >> 6, lane = tid & 63;
    int quad = lane >> 4, m = lane & 15;
    for (int tile = blockIdx.x; tile < ntiles; tile += gridDim.x) {
        int r0 = tile * 64 + wave * 16;
        int row = min(r0 + m, N - 1);
        f32x4 acc[4];
#pragma unroll
        for (int c = 0; c < 4; ++c) acc[c] = {0.f, 0.f, 0.f, 0.f};
        const bf16x8* mrow = (const bf16x8*)(mb + (size_t)row * 128);
        const bf16x8* hrow = (const bf16x8*)(hb + (size_t)row * 128);
#pragma unroll
        for (int step = 0; step < 4; ++step) {
            bf16x8 af = mrow[step * 4 + quad];
#pragma unroll
            for (int c = 0; c < 4; ++c) {
                bf16x8 bf = *(const bf16x8*)&sB[c * 16 + m][step * 32 + quad * 8];
                acc[c] = __builtin_amdgcn_mfma_f32_16x16x32_bf16(bf, af, acc[c], 0, 0, 0);
            }
        }
#pragma unroll
        for (int step = 0; step < 4; ++step) {
            bf16x8 af = hrow[step * 4 + quad];
#pragma unroll
            for (int c = 0; c < 4; ++c) {
                bf16x8 bf = *(const bf16x8*)&sB[c * 16 + m][128 + step * 32 + quad * 8];
                acc[c] = __builtin_amdgcn_mfma_f32_16x16x32_bf16(bf, af, acc[c], 0, 0, 0);
            }
        }
        // +bias (channel = c*16 + quad*4 + reg)
#pragma unroll
        for (int c = 0; c < 4; ++c) {
            float4 b4 = *(const float4*)&bl[c * 16 + quad * 4];
            acc[c][0] += b4.x; acc[c][1] += b4.y; acc[c][2] += b4.z; acc[c][3] += b4.w;
        }
        // log_softmax: row r0+m spans lanes {m, m+16, m+32, m+48}
        float mx = -1e30f;
#pragma unroll
        for (int c = 0; c < 4; ++c)
            mx = fmaxf(mx, fmaxf(fmaxf(acc[c][0], acc[c][1]), fmaxf(acc[c][2], acc[c][3])));
        mx = fmaxf(mx, __shfl_xor(mx, 16));
        mx = fmaxf(mx, __shfl_xor(mx, 32));
        float sm = 0.f;
#pragma unroll
        for (int c = 0; c < 4; ++c)
            sm += expf(acc[c][0] - mx) + expf(acc[c][1] - mx) +
                  expf(acc[c][2] - mx) + expf(acc[c][3] - mx);
        sm += __shfl_xor(sm, 16);
        sm += __shfl_xor(sm, 32);
        float lse = mx + logf(sm);
        int r = r0 + m;
        if (r < N) {
#pragma unroll
            for (int c = 0; c < 4; ++c) {
                float4 o = {acc[c][0] - lse, acc[c][1] - lse,
                            acc[c][2] - lse, acc[c][3] - lse};
                *(float4*)&out[(size_t)r * 64 + c * 16 + quad * 4] = o;
            }
        }
    }
}

extern "C" void kernel_launch(void* const* d_in, const int* in_sizes, int n_in,
                              void* d_out, int out_size, void* d_ws, size_t ws_size,
                              hipStream_t stream) {
    const float* x   = (const float*)d_in[0];
    const int*   ei  = (const int*)d_in[1];
    const float* Wl1 = (const float*)d_in[2];
    const float* bl1 = (const float*)d_in[3];
    const float* Wr1 = (const float*)d_in[4];
    const float* Wl2 = (const float*)d_in[5];
    const float* bl2 = (const float*)d_in[6];
    const float* Wr2 = (const float*)d_in[7];

    int N = in_sizes[0] / IN_C;
    int E = in_sizes[1] / 2;
    const int* src = ei;
    const int* dst = ei + E;

    // ws (32.8 MB + 16 B): counts i32[N] | offs i32[N] | csr i32[E] | mean bf16[N*128] | total i32[4]
    int* counts = (int*)d_ws;
    int* offs   = counts + N;
    int* csr    = offs + N;
    unsigned short* mean = (unsigned short*)(csr + E);
    int* total  = (int*)(mean + (size_t)N * 128);
    // d_out (25.6 MB) sequentially holds: xb bf16[N*128] -> hb bf16[N*128] -> out f32[N*64]
    unsigned short* xb = (unsigned short*)d_out;
    unsigned short* hb = (unsigned short*)d_out;
    float* out = (float*)d_out;

    hipMemsetAsync(counts, 0, (size_t)N * sizeof(int), stream);
    hipMemsetAsync(total, 0, sizeof(int), stream);

    int eblocks = (E + 255) / 256;
    hist_kernel<<<eblocks, 256, 0, stream>>>(dst, counts, E);
    alloc_kernel<<<(N + 255) / 256, 256, 0, stream>>>(counts, offs, total, N);
    int nchunks = (E + BK_CHUNK - 1) / BK_CHUNK;
    bucket_kernel<<<nchunks * 8, 256, 0, stream>>>(src, dst, offs, csr, E, N);

    // x -> bf16
    convert_kernel<<<(N * IN_C) / (256 * 8), 256, 0, stream>>>(x, xb);

    int ntiles = (N + 63) / 64;
    int gblocks = (N * 16 + 255) / 256;  // 16 lanes/row

    // Layer 1
    agg_mean_kernel<<<gblocks, 256, 0, stream>>>(xb, counts, offs, csr, mean, N);
    gemm1_mfma_kernel<<<512, 256, 0, stream>>>(mean, xb, Wl1, bl1, Wr1, hb, N, ntiles);

    // Layer 2
    agg_mean_kernel<<<gblocks, 256, 0, stream>>>(hb, counts, offs, csr, mean, N);
    gemm2_mfma_kernel<<<512, 256, 0, stream>>>(mean, hb, Wl2, bl2, Wr2, out, N, ntiles);
}